// Round 1
// baseline (148.322 us; speedup 1.0000x reference)
//
#include <hip/hip_runtime.h>

#define TILE      64
#define NTHREADS  256
#define STRIDE    85      // 5 + NUM_CLASSES
#define NCLS      80
#define SSPAN     2704    // S*S = 52*52
#define NANCH     3
#define MAXGRID   2028

__device__ __forceinline__ float wave_reduce(float v) {
    #pragma unroll
    for (int off = 32; off > 0; off >>= 1)
        v += __shfl_down(v, off, 64);
    return v;
}

__global__ __launch_bounds__(NTHREADS) void loss_partial(
    const float* __restrict__ pred, const float* __restrict__ tgt,
    const float* __restrict__ anchors, float* __restrict__ partial,
    int n_cells, int n_tiles)
{
    __shared__ float lds_p[TILE * STRIDE];   // 5440 floats = 21.25 KB
    __shared__ float lds_t[TILE * 6];        // 384 floats
    __shared__ float red[4][6];

    const int tid  = threadIdx.x;
    const int lane = tid & 63;
    const int wid  = tid >> 6;
    const int cell_l = tid >> 2;   // 0..63
    const int part   = tid & 3;    // 0..3, 20 classes each

    float a_obj = 0.f, a_nobj = 0.f, a_bceo = 0.f, a_bceno = 0.f,
          a_box = 0.f, a_cls = 0.f;

    for (int tile = blockIdx.x; tile < n_tiles; tile += gridDim.x) {
        const int base = tile * TILE;

        // ---- stage tile: coalesced float4 ----
        if (base + TILE <= n_cells) {
            const float4* gp = (const float4*)(pred + (size_t)base * STRIDE);
            float4* lp = (float4*)lds_p;
            for (int i = tid; i < (TILE * STRIDE) / 4; i += NTHREADS) lp[i] = gp[i];
            const float4* gt = (const float4*)(tgt + (size_t)base * 6);
            float4* lt = (float4*)lds_t;
            if (tid < (TILE * 6) / 4) lt[tid] = gt[tid];
        } else {
            const int nv = n_cells - base;           // < TILE
            for (int i = tid; i < nv * STRIDE; i += NTHREADS)
                lds_p[i] = pred[(size_t)base * STRIDE + i];
            for (int i = tid; i < nv * 6; i += NTHREADS)
                lds_t[i] = tgt[(size_t)base * 6 + i];
        }
        __syncthreads();

        const int cell_g = base + cell_l;
        const bool active = (cell_g < n_cells);

        // ---- class softmax partial: 20 logits in registers ----
        float v[20];
        const float* cp = lds_p + cell_l * STRIDE + 5 + part * 20;
        #pragma unroll
        for (int k = 0; k < 20; ++k) v[k] = cp[k];
        float mx = v[0];
        #pragma unroll
        for (int k = 1; k < 20; ++k) mx = fmaxf(mx, v[k]);
        mx = fmaxf(mx, __shfl_xor(mx, 1, 64));
        mx = fmaxf(mx, __shfl_xor(mx, 2, 64));
        float se = 0.f;
        #pragma unroll
        for (int k = 0; k < 20; ++k) se += __expf(v[k] - mx);
        se += __shfl_xor(se, 1, 64);
        se += __shfl_xor(se, 2, 64);

        if (part == 0 && active) {
            const float* pc = lds_p + cell_l * STRIDE;
            const float* tc = lds_t + cell_l * 6;
            const float p0 = pc[0], t0 = tc[0];
            const float bce_base = fmaxf(p0, 0.f) + log1pf(expf(-fabsf(p0)));
            if (t0 == 0.0f) { a_nobj += 1.f; a_bceno += bce_base; }
            if (t0 == 1.0f) {
                a_obj += 1.f;
                const int aidx = (cell_g / SSPAN) % NANCH;
                const float aw = anchors[aidx * 2], ah = anchors[aidx * 2 + 1];
                const float p1 = pc[1], p2 = pc[2], p3 = pc[3], p4 = pc[4];
                const float t1 = tc[1], t2 = tc[2], t3 = tc[3], t4 = tc[4];
                const float sx = 1.f / (1.f + expf(-p1));
                const float sy = 1.f / (1.f + expf(-p2));
                const float pw = expf(p3) * aw, ph = expf(p4) * ah;
                // IoU (center format), computed as the reference does
                const float b1x1 = sx - pw * 0.5f, b1x2 = sx + pw * 0.5f;
                const float b1y1 = sy - ph * 0.5f, b1y2 = sy + ph * 0.5f;
                const float b2x1 = t1 - t3 * 0.5f, b2x2 = t1 + t3 * 0.5f;
                const float b2y1 = t2 - t4 * 0.5f, b2y2 = t2 + t4 * 0.5f;
                const float iw = fmaxf(fminf(b1x2, b2x2) - fmaxf(b1x1, b2x1), 0.f);
                const float ih = fmaxf(fminf(b1y2, b2y2) - fmaxf(b1y1, b2y1), 0.f);
                const float inter = iw * ih;
                const float uni = (b1x2 - b1x1) * (b1y2 - b1y1)
                                + (b2x2 - b2x1) * (b2y2 - b2y1) - inter;
                const float iou = inter / (uni + 1e-16f);
                // obj BCE vs IoU-scaled target (t0==1 -> y=iou)
                a_bceo += bce_base - p0 * iou;
                // box MSE
                const float lw = logf(1e-16f + t3 / aw);
                const float lh = logf(1e-16f + t4 / ah);
                const float d0 = sx - t1, d1 = sy - t2, d2 = p3 - lw, d3 = p4 - lh;
                a_box += d0 * d0 + d1 * d1 + d2 * d2 + d3 * d3;
                // class NLL
                const int label = (int)tc[5];
                a_cls += (mx + logf(se)) - pc[5 + label];
            }
        }
        __syncthreads();
    }

    // ---- block reduction -> per-block partial ----
    float vals[6] = {a_obj, a_nobj, a_bceo, a_bceno, a_box, a_cls};
    #pragma unroll
    for (int k = 0; k < 6; ++k) {
        const float r = wave_reduce(vals[k]);
        if (lane == 0) red[wid][k] = r;
    }
    __syncthreads();
    if (tid == 0) {
        #pragma unroll
        for (int k = 0; k < 6; ++k)
            partial[blockIdx.x * 6 + k] =
                red[0][k] + red[1][k] + red[2][k] + red[3][k];
    }
}

__global__ __launch_bounds__(NTHREADS) void loss_final(
    const float* __restrict__ partial, int nblocks, float* __restrict__ out)
{
    __shared__ float red[4][6];
    const int tid = threadIdx.x, lane = tid & 63, wid = tid >> 6;
    float s[6] = {0.f, 0.f, 0.f, 0.f, 0.f, 0.f};
    for (int i = tid; i < nblocks; i += NTHREADS) {
        #pragma unroll
        for (int k = 0; k < 6; ++k) s[k] += partial[i * 6 + k];
    }
    #pragma unroll
    for (int k = 0; k < 6; ++k) {
        const float r = wave_reduce(s[k]);
        if (lane == 0) red[wid][k] = r;
    }
    __syncthreads();
    if (tid == 0) {
        float t[6];
        #pragma unroll
        for (int k = 0; k < 6; ++k)
            t[k] = red[0][k] + red[1][k] + red[2][k] + red[3][k];
        const float n_obj = t[0], n_noobj = t[1];
        const float detection = t[2] / n_obj;
        const float no_det    = t[3] / n_noobj;
        const float box       = t[4] / (4.f * n_obj);
        const float cls       = t[5] / n_obj;
        out[0] = box + detection + no_det + cls;
    }
}

extern "C" void kernel_launch(void* const* d_in, const int* in_sizes, int n_in,
                              void* d_out, int out_size, void* d_ws, size_t ws_size,
                              hipStream_t stream) {
    const float* pred    = (const float*)d_in[0];
    const float* tgt     = (const float*)d_in[1];
    const float* anchors = (const float*)d_in[2];
    float* out = (float*)d_out;

    const int n_cells = in_sizes[1] / 6;                 // 259584
    const int n_tiles = (n_cells + TILE - 1) / TILE;     // 4056
    const int grid = n_tiles < MAXGRID ? n_tiles : MAXGRID;
    float* partial = (float*)d_ws;                       // grid*6 floats

    loss_partial<<<grid, NTHREADS, 0, stream>>>(pred, tgt, anchors, partial,
                                                n_cells, n_tiles);
    loss_final<<<1, NTHREADS, 0, stream>>>(partial, grid, out);
}